// Round 3
// baseline (605.724 us; speedup 1.0000x reference)
//
#include <hip/hip_runtime.h>
#include <cstdint>
#include <cstddef>

typedef short s16x8 __attribute__((ext_vector_type(8)));
typedef float f32x4 __attribute__((ext_vector_type(4)));
typedef unsigned short u16;

// ---------- fp32 -> bf16 (RNE) ----------
static __device__ __forceinline__ u16 f2bf(float f) {
  union { float f; unsigned u; } c; c.f = f;
  unsigned u = c.u;
  u += 0x7FFFu + ((u >> 16) & 1u);
  return (u16)(u >> 16);
}

// Fused convert: one launch covers both tensors (BW-bound, ~55 us).
__global__ __launch_bounds__(256) void cvt_all_kernel(
    const float* __restrict__ x, u16* __restrict__ xo,
    const int* __restrict__ w,   u16* __restrict__ wo,
    int xblocks) {
  union { u16 h[4]; uint2 v; } r;
  if (blockIdx.x < xblocks) {
    const size_t i = (size_t)blockIdx.x * 256 + threadIdx.x;
    float4 a = ((const float4*)x)[i];
    r.h[0] = f2bf(a.x); r.h[1] = f2bf(a.y); r.h[2] = f2bf(a.z); r.h[3] = f2bf(a.w);
    ((uint2*)xo)[i] = r.v;
  } else {
    const size_t i = (size_t)(blockIdx.x - xblocks) * 256 + threadIdx.x;
    int4 a = ((const int4*)w)[i];
    r.h[0] = f2bf((float)a.x); r.h[1] = f2bf((float)a.y);
    r.h[2] = f2bf((float)a.z); r.h[3] = f2bf((float)a.w);
    ((uint2*)wo)[i] = r.v;
  }
}

// ---------- async global->LDS, 16B per lane, wave-uniform LDS base ----------
static __device__ __forceinline__ void gld_lds16(const void* g, void* l) {
  __builtin_amdgcn_global_load_lds(
      (const __attribute__((address_space(1))) unsigned int*)g,
      (__attribute__((address_space(3))) unsigned int*)l,
      16, 0, 0);
}

// ---------- bf16 NT GEMM: C[m][n] = scaler[n] * sum_k A[m][k]*B[n][k] ----------
// block = 256 thr (4 waves), tile 128x128, BK=32. LDS 2x8KB.
// R2 counters: LDS pipe was the top consumer (57% incl. 3.35e7 conflict
// cycles). Rows are 64B=16 dwords -> read offsets alias 4-bank groups.
// Fix: XOR-swizzle 16B chunks. Staging lane l loads global chunk
// (l&3)^((row>>1)&3) of its row (global_load_lds stores at lane*16, so
// the LDS layout is chunk-permuted); reader compensates with q^((r16>>1)&3).
// Within every 8-lane group all 8 bank-quad starts become distinct.
__global__ __launch_bounds__(256) void gemm_bt_kernel(
    const u16* __restrict__ A,      // [M,K] bf16
    const u16* __restrict__ B,      // [N,K] bf16
    const float* __restrict__ scaler,
    float* __restrict__ C,          // [M,N] fp32
    int M, int N, int K) {
  __shared__ __align__(16) u16 As[128 * 32];
  __shared__ __align__(16) u16 Bs[128 * 32];

  const int tid  = threadIdx.x;
  const int lane = tid & 63;
  const int wave = tid >> 6;
  const int wm   = wave >> 1;     // wave row (0..1) -> 64 rows of M
  const int wn   = wave & 1;      // wave col (0..1) -> 64 cols of N
  const int q    = lane >> 4;     // quad 0..3
  const int r16  = lane & 15;

  const int m0 = blockIdx.y * 128;
  const int n0 = blockIdx.x * 128;

  f32x4 acc[4][4];
#pragma unroll
  for (int i = 0; i < 4; ++i)
#pragma unroll
    for (int j = 0; j < 4; ++j) acc[i][j] = (f32x4){0.f, 0.f, 0.f, 0.f};

  // staging: thread t -> row t>>2, swizzled 16B chunk (t&3)^((row>>1)&3).
  // (row>>1)&3 == (t>>3)&3; +64-row half keeps the same value (64>>1=32,
  // 32&3==0), so one lane mapping serves both gld_lds16 calls.
  const int  crow = tid >> 2;                              // 0..63
  const int  ccol = (((tid & 3) ^ ((tid >> 3) & 3)) * 16); // swizzled byte offset
  const size_t rsA = (size_t)K * 2;      // row stride bytes
  const char* Ag = (const char*)A + ((size_t)m0 + crow) * rsA + ccol;
  const char* Bg = (const char*)B + ((size_t)n0 + crow) * rsA + ccol;
  const size_t half = 64 * rsA;          // +64 rows

  char* AsW = (char*)As + wave * 1024;   // wave-uniform LDS bases
  char* BsW = (char*)Bs + wave * 1024;

  // LDS read offsets (elements): row-major [128][32] with chunk swizzle.
  // Wanted chunk q of row (wm*64 + mt*16 + r16); mt*16 and wm*64 are
  // 0 mod 8 after >>1, so the swizzle term is q ^ ((r16>>1)&3) for all mt.
  const int sw   = (r16 >> 1) & 3;
  const int aoff = (wm * 64 + r16) * 32 + (q ^ sw) * 8;
  const int boff = (wn * 64 + r16) * 32 + (q ^ sw) * 8;

  for (int k0 = 0; k0 < K; k0 += 32) {
    const size_t kb = (size_t)k0 * 2;
    gld_lds16(Ag + kb,        AsW);
    gld_lds16(Ag + kb + half, AsW + 4096);
    gld_lds16(Bg + kb,        BsW);
    gld_lds16(Bg + kb + half, BsW + 4096);
    __syncthreads();   // drains vmcnt -> tiles visible

    s16x8 af[4], bfr[4];
#pragma unroll
    for (int mt = 0; mt < 4; ++mt)
      af[mt] = *(const s16x8*)(As + aoff + mt * (16 * 32));
#pragma unroll
    for (int nt = 0; nt < 4; ++nt)
      bfr[nt] = *(const s16x8*)(Bs + boff + nt * (16 * 32));
#pragma unroll
    for (int mt = 0; mt < 4; ++mt)
#pragma unroll
      for (int nt = 0; nt < 4; ++nt)
        acc[mt][nt] = __builtin_amdgcn_mfma_f32_16x16x32_bf16(
            af[mt], bfr[nt], acc[mt][nt], 0, 0, 0);
    __syncthreads();   // protect LDS before next overwrite
  }

  // epilogue: C/D layout col=lane&15, row=(lane>>4)*4+reg; scale by scaler[n]
#pragma unroll
  for (int nt = 0; nt < 4; ++nt) {
    const int col = n0 + wn * 64 + nt * 16 + r16;
    const float s = scaler[col];
#pragma unroll
    for (int mt = 0; mt < 4; ++mt) {
      const int row0 = m0 + wm * 64 + mt * 16 + q * 4;
      float* Cp = C + (size_t)row0 * N + col;
#pragma unroll
      for (int r = 0; r < 4; ++r)
        Cp[(size_t)r * N] = acc[mt][nt][r] * s;
    }
  }
}

// ---------- fallback (only if ws too small / odd shape) ----------
__global__ void naive_kernel(const float* __restrict__ x, const int* __restrict__ w,
                             const float* __restrict__ sc, float* __restrict__ out,
                             int M, int N, int K) {
  int idx = blockIdx.x * 256 + threadIdx.x;
  if (idx >= M * N) return;
  int m = idx / N, n = idx % N;
  const float* xr = x + (size_t)m * K;
  const int*   wr = w + (size_t)n * K;
  float acc = 0.f;
  for (int k = 0; k < K; ++k) acc += xr[k] * (float)wr[k];
  out[idx] = acc * sc[n];
}

extern "C" void kernel_launch(void* const* d_in, const int* in_sizes, int n_in,
                              void* d_out, int out_size, void* d_ws, size_t ws_size,
                              hipStream_t stream) {
  const float* x  = (const float*)d_in[0];
  const int*   w  = (const int*)d_in[1];
  const float* sc = (const float*)d_in[2];
  float* out = (float*)d_out;

  const int N = in_sizes[2];          // D_OUT
  const int K = in_sizes[1] / N;      // D_IN
  const int M = in_sizes[0] / K;      // B*S

  const size_t need = ((size_t)M * K + (size_t)N * K) * sizeof(u16);
  if (ws_size < need || (M % 128) || (N % 128) || (K % 32) ||
      (((size_t)M * K) % 1024) || (((size_t)N * K) % 1024)) {
    int total = M * N;
    naive_kernel<<<(total + 255) / 256, 256, 0, stream>>>(x, w, sc, out, M, N, K);
    return;
  }

  u16* xb = (u16*)d_ws;
  u16* wb = xb + (size_t)M * K;

  const int xblocks = (int)(((size_t)M * K) / 1024);
  const int wblocks = (int)(((size_t)N * K) / 1024);
  cvt_all_kernel<<<xblocks + wblocks, 256, 0, stream>>>(x, xb, w, wb, xblocks);

  dim3 grid(N / 128, M / 128);
  gemm_bt_kernel<<<grid, 256, 0, stream>>>(xb, wb, sc, out, M, N, K);
}

// Round 4
// 459.166 us; speedup vs baseline: 1.3192x; 1.3192x over previous
//
#include <hip/hip_runtime.h>
#include <cstdint>
#include <cstddef>

typedef int i32x4 __attribute__((ext_vector_type(4)));

// ---------- prep: one launch quantizes x (per-row symmetric int8) and packs w ----------
//  blocks [0, xrows)   : x row b -> int8 + scale  (two passes over the 16KB row, 2nd is L1-hot)
//  blocks [xrows, ...) : w int32 -> int8, 4 ints -> 1 dword per thread, fully coalesced
__global__ __launch_bounds__(256) void prep_kernel(
    const float* __restrict__ x, signed char* __restrict__ xq, float* __restrict__ xs,
    const int* __restrict__ w, signed char* __restrict__ wq,
    int K, int xrows) {
  const int t = threadIdx.x;
  if ((int)blockIdx.x < xrows) {
    const int row = blockIdx.x;
    const float4* xr = (const float4*)(x + (size_t)row * K);
    const int n4 = K >> 2;
    float amax = 0.f;
    for (int i = t; i < n4; i += 256) {
      float4 v = xr[i];
      amax = fmaxf(amax, fmaxf(fmaxf(fabsf(v.x), fabsf(v.y)),
                               fmaxf(fabsf(v.z), fabsf(v.w))));
    }
#pragma unroll
    for (int off = 32; off > 0; off >>= 1)
      amax = fmaxf(amax, __shfl_xor(amax, off, 64));
    __shared__ float wmax[4];
    if ((t & 63) == 0) wmax[t >> 6] = amax;
    __syncthreads();
    amax = fmaxf(fmaxf(wmax[0], wmax[1]), fmaxf(wmax[2], wmax[3]));
    const float inv = (amax > 0.f) ? 127.f / amax : 0.f;
    if (t == 0) xs[row] = amax / 127.f;
    int* o = (int*)(xq + (size_t)row * K);
    for (int i = t; i < n4; i += 256) {
      float4 v = xr[i];                      // L1-hot re-read
      int a = __float2int_rn(v.x * inv) & 0xFF;
      int b = __float2int_rn(v.y * inv) & 0xFF;
      int c = __float2int_rn(v.z * inv) & 0xFF;
      int d = __float2int_rn(v.w * inv) & 0xFF;
      o[i] = a | (b << 8) | (c << 16) | (d << 24);
    }
  } else {
    const size_t g = (size_t)(blockIdx.x - xrows) * 256 + t;  // dword granule
    int4 v = ((const int4*)w)[g];
    ((int*)wq)[g] = (v.x & 0xFF) | ((v.y & 0xFF) << 8) |
                    ((v.z & 0xFF) << 16) | ((v.w & 0xFF) << 24);
  }
}

// ---------- async global->LDS, 16B per lane, wave-uniform LDS base ----------
static __device__ __forceinline__ void gld_lds16(const void* g, void* l) {
  __builtin_amdgcn_global_load_lds(
      (const __attribute__((address_space(1))) unsigned int*)g,
      (__attribute__((address_space(3))) unsigned int*)l,
      16, 0, 0);
}

// ---------- i8 NT GEMM: C[m][n] = xs[m]*ws[n] * sum_k Aq[m][k]*Bq[n][k] ----------
// 256 thr / 4 waves, tile 128x128, BK=64 (i8: rows stay 64B -> identical LDS
// geometry to the bf16 version, half the iterations/reads/staging bytes,
// MFMA at 2x ops/inst). mfma_i32_16x16x64_i8: A/B 4 VGPRs = 16 i8/lane,
// k=(lane>>4)*16+j (gfx950 2xK pattern); C/D col=lane&15,row=(lane>>4)*4+reg
// (dtype-independent, verified). int32 dot is exact: K*127^2 < 2^31.
// XOR chunk swizzle carried over from R3 (conflicts measured 0).
__global__ __launch_bounds__(256) void gemm_i8_kernel(
    const signed char* __restrict__ A,   // [M,K] i8
    const signed char* __restrict__ B,   // [N,K] i8
    const float* __restrict__ xs,        // [M] row scales
    const float* __restrict__ ws,        // [N] col scales
    float* __restrict__ C,               // [M,N] fp32
    int M, int N, int K) {
  __shared__ __align__(16) signed char As[128 * 64];
  __shared__ __align__(16) signed char Bs[128 * 64];

  const int tid  = threadIdx.x;
  const int lane = tid & 63;
  const int wave = tid >> 6;
  const int wm   = wave >> 1;
  const int wn   = wave & 1;
  const int q    = lane >> 4;
  const int r16  = lane & 15;

  const int m0 = blockIdx.y * 128;
  const int n0 = blockIdx.x * 128;

  i32x4 acc[4][4];
#pragma unroll
  for (int i = 0; i < 4; ++i)
#pragma unroll
    for (int j = 0; j < 4; ++j) acc[i][j] = (i32x4){0, 0, 0, 0};

  // staging: thread t -> row t>>2 (64B), swizzled 16B chunk (t&3)^((t>>3)&3)
  const int  crow = tid >> 2;
  const int  ccol = (((tid & 3) ^ ((tid >> 3) & 3)) * 16);
  const size_t rs = (size_t)K;                 // row stride bytes (i8)
  const char* Ag = (const char*)A + ((size_t)m0 + crow) * rs + ccol;
  const char* Bg = (const char*)B + ((size_t)n0 + crow) * rs + ccol;
  const size_t half = 64 * rs;

  char* AsW = (char*)As + wave * 1024;
  char* BsW = (char*)Bs + wave * 1024;

  // reader: row r, K-chunk q (16 i8), swizzle-compensated
  const int sw   = (r16 >> 1) & 3;
  const int aoff = (wm * 64 + r16) * 64 + (q ^ sw) * 16;   // byte offsets
  const int boff = (wn * 64 + r16) * 64 + (q ^ sw) * 16;

  for (int k0 = 0; k0 < K; k0 += 64) {
    gld_lds16(Ag + k0,        AsW);
    gld_lds16(Ag + k0 + half, AsW + 4096);
    gld_lds16(Bg + k0,        BsW);
    gld_lds16(Bg + k0 + half, BsW + 4096);
    __syncthreads();

    i32x4 af[4], bfr[4];
#pragma unroll
    for (int mt = 0; mt < 4; ++mt)
      af[mt] = *(const i32x4*)(As + aoff + mt * (16 * 64));
#pragma unroll
    for (int nt = 0; nt < 4; ++nt)
      bfr[nt] = *(const i32x4*)(Bs + boff + nt * (16 * 64));
#pragma unroll
    for (int mt = 0; mt < 4; ++mt)
#pragma unroll
      for (int nt = 0; nt < 4; ++nt)
        acc[mt][nt] = __builtin_amdgcn_mfma_i32_16x16x64_i8(
            af[mt], bfr[nt], acc[mt][nt], 0, 0, 0);
    __syncthreads();
  }

  // epilogue: C/D col=lane&15, row=(lane>>4)*4+reg; out = acc * xs[row] * ws[col]
  float xsv[4][4];
#pragma unroll
  for (int mt = 0; mt < 4; ++mt) {
    const int row0 = m0 + wm * 64 + mt * 16 + q * 4;
#pragma unroll
    for (int r = 0; r < 4; ++r) xsv[mt][r] = xs[row0 + r];
  }
#pragma unroll
  for (int nt = 0; nt < 4; ++nt) {
    const int col = n0 + wn * 64 + nt * 16 + r16;
    const float s = ws[col];
#pragma unroll
    for (int mt = 0; mt < 4; ++mt) {
      const int row0 = m0 + wm * 64 + mt * 16 + q * 4;
      float* Cp = C + (size_t)row0 * N + col;
#pragma unroll
      for (int r = 0; r < 4; ++r)
        Cp[(size_t)r * N] = (float)acc[mt][nt][r] * xsv[mt][r] * s;
    }
  }
}

// ---------- fallback (odd shapes / tiny ws) ----------
__global__ void naive_kernel(const float* __restrict__ x, const int* __restrict__ w,
                             const float* __restrict__ sc, float* __restrict__ out,
                             int M, int N, int K) {
  int idx = blockIdx.x * 256 + threadIdx.x;
  if (idx >= M * N) return;
  int m = idx / N, n = idx % N;
  const float* xr = x + (size_t)m * K;
  const int*   wr = w + (size_t)n * K;
  float acc = 0.f;
  for (int k = 0; k < K; ++k) acc += xr[k] * (float)wr[k];
  out[idx] = acc * sc[n];
}

extern "C" void kernel_launch(void* const* d_in, const int* in_sizes, int n_in,
                              void* d_out, int out_size, void* d_ws, size_t ws_size,
                              hipStream_t stream) {
  const float* x  = (const float*)d_in[0];
  const int*   w  = (const int*)d_in[1];
  const float* sc = (const float*)d_in[2];
  float* out = (float*)d_out;

  const int N = in_sizes[2];          // D_OUT
  const int K = in_sizes[1] / N;      // D_IN
  const int M = in_sizes[0] / K;      // B*S

  const size_t need = (size_t)M * K + (size_t)N * K + (size_t)M * 4 + 16;
  if (ws_size < need || (M % 128) || (N % 128) || (K % 64) || (K % 16) ||
      (((size_t)N * K) % 1024)) {
    int total = M * N;
    naive_kernel<<<(total + 255) / 256, 256, 0, stream>>>(x, w, sc, out, M, N, K);
    return;
  }

  signed char* xq = (signed char*)d_ws;
  signed char* wq = xq + (size_t)M * K;
  float*       xsc = (float*)(wq + (size_t)N * K);

  const int wblocks = (int)(((size_t)N * K) / 1024);  // 4 ints/thread
  prep_kernel<<<M + wblocks, 256, 0, stream>>>(x, xq, xsc, w, wq, K, M);

  dim3 grid(N / 128, M / 128);
  gemm_i8_kernel<<<grid, 256, 0, stream>>>(xq, wq, xsc, sc, out, M, N, K);
}